// Round 3
// baseline (225.125 us; speedup 1.0000x reference)
//
#include <hip/hip_runtime.h>
#include <hip/hip_bf16.h>

#define N_NODES 30000
#define N_EDGES 120000
#define IN_DIM  9
#define H       32
#define G_GRAPHS 256
#define NSTEP   66   // K = 33*32 = 1056, K-step 16

typedef __attribute__((ext_vector_type(8)))  short short8v;
typedef __attribute__((ext_vector_type(16))) float f32x16;

__device__ __forceinline__ unsigned short bfb(float x) {
    __hip_bfloat16 h = __float2bfloat16(x);
    return __builtin_bit_cast(unsigned short, h);
}

// ------------------------------------------------- weights -> bf16 frag order
// bfrag[k][step][lane][t] = Wf_k[step*16 + (lane>>5)*8 + t , lane&31]
// Wf_k = [Wnn_k (1024x32); bnn_k (32x32)]
__global__ __launch_bounds__(256) void wconv_k(
    const float* __restrict__ Wnn, const float* __restrict__ bnn,
    unsigned short* __restrict__ bfrag)
{
    int gid = blockIdx.x * 256 + threadIdx.x;
    if (gid >= 3 * NSTEP * 512) return;
    int layer = gid / (NSTEP * 512);
    int rem   = gid % (NSTEP * 512);
    int step  = rem >> 9;
    int lane  = (rem >> 3) & 63;
    int t     = gid & 7;
    int krow  = step * 16 + ((lane >> 5) << 3) + t;   // 0..1055
    int col   = lane & 31;
    float v = (krow < 1024) ? Wnn[layer * 32768 + krow * 32 + col]
                            : bnn[layer * 1024 + (krow - 1024) * 32 + col];
    bfrag[gid] = bfb(v);
}

// ---------------------------------------------------------------- node embed
__global__ __launch_bounds__(256) void node_embed_k(
    const float* __restrict__ x, const float* __restrict__ Wn,
    const float* __restrict__ bn, float* __restrict__ s)
{
    int gid = blockIdx.x * 256 + threadIdx.x;
    if (gid >= N_NODES * H) return;
    int n = gid >> 5, o = gid & 31;
    float acc = bn[o];
    #pragma unroll
    for (int i = 0; i < IN_DIM; ++i)
        acc = fmaf(x[n * IN_DIM + i], Wn[i * H + o], acc);
    s[gid] = fmaxf(acc, 0.f);
}

// ------------------------------------------------------ counting sort by dst
__global__ __launch_bounds__(256) void hist_k(
    const int* __restrict__ dst, int* __restrict__ hist)
{
    int e = blockIdx.x * 256 + threadIdx.x;
    if (e < N_EDGES) atomicAdd(&hist[dst[e]], 1);
}

// 1-block exclusive scan over 30000 counters -> cursor
__global__ __launch_bounds__(1024) void scan_k(
    const int* __restrict__ hist, int* __restrict__ cursor)
{
    __shared__ int wsum[16];
    const int t = threadIdx.x;
    const int lane = t & 63, wid = t >> 6;
    const int CH = 30;                       // 1024*30 = 30720 >= 30000
    const int base = t * CH;
    int v[CH]; int sum = 0;
    #pragma unroll
    for (int i = 0; i < CH; ++i) {
        int idx = base + i;
        int x = (idx < N_NODES) ? hist[idx] : 0;
        v[i] = x; sum += x;
    }
    int incl = sum;
    #pragma unroll
    for (int off = 1; off < 64; off <<= 1) {
        int tmp = __shfl_up(incl, off);
        if (lane >= off) incl += tmp;
    }
    if (lane == 63) wsum[wid] = incl;
    __syncthreads();
    if (wid == 0 && lane < 16) {
        int wv = wsum[lane];
        #pragma unroll
        for (int off = 1; off < 16; off <<= 1) {
            int tmp = __shfl_up(wv, off);
            if (lane >= off) wv += tmp;
        }
        wsum[lane] = wv;                     // inclusive wave totals
    }
    __syncthreads();
    int excl = incl - sum + (wid > 0 ? wsum[wid - 1] : 0);
    int run = excl;
    #pragma unroll
    for (int i = 0; i < CH; ++i) {
        int idx = base + i;
        if (idx < N_NODES) cursor[idx] = run;
        run += v[i];
    }
}

__global__ __launch_bounds__(256) void scatter_k(
    const int* __restrict__ dst, int* __restrict__ cursor,
    int* __restrict__ sorted_eid, int* __restrict__ dst_sorted)
{
    int e = blockIdx.x * 256 + threadIdx.x;
    if (e >= N_EDGES) return;
    int d = dst[e];
    int pos = atomicAdd(&cursor[d], 1);
    sorted_eid[pos] = e;
    dst_sorted[pos] = d;
}

// ------------------------------------------------------------ edge conv MFMA
// Wave tile: 64 dst-sorted edges = 2 M-tiles of 32. msg = Z @ Wf.
// A-frag: row=lane&31 (edge), k=(lane>>5)*8+t
// D-frag: col=lane&31 (=o), row=(reg&3)+8*(reg>>2)+4*(lane>>5)
__global__ __launch_bounds__(256) void edge_mfma_k(
    const float* __restrict__ s, const float* __restrict__ eattr,
    const int* __restrict__ ei, const float* __restrict__ We,
    const float* __restrict__ be, const unsigned short* __restrict__ bfrag,
    const int* __restrict__ sorted_eid, const int* __restrict__ dst_sorted,
    float* __restrict__ agg)
{
    const int wave = threadIdx.x >> 6;
    const int lane = threadIdx.x & 63;
    const int ebase = blockIdx.x * 256 + wave * 64;
    if (ebase >= N_EDGES) return;            // 120000 % 64 == 0
    const int er = lane & 31;
    const int hi = lane >> 5;

    const int e0 = sorted_eid[ebase + er];
    const int e1 = sorted_eid[ebase + 32 + er];

    const float a00 = eattr[e0 * 3 + 0], a01 = eattr[e0 * 3 + 1], a02 = eattr[e0 * 3 + 2];
    const float a10 = eattr[e1 * 3 + 0], a11 = eattr[e1 * 3 + 1], a12 = eattr[e1 * 3 + 2];

    const int src0 = ei[e0], src1 = ei[e1];

    float h0[16], h1[16];
    {
        const float* r0 = s + src0 * H + hi * 8;
        const float* r1 = s + src1 * H + hi * 8;
        #pragma unroll
        for (int q = 0; q < 2; ++q) {
            float4 u0 = *(const float4*)(r0 + q * 16);
            float4 u1 = *(const float4*)(r0 + q * 16 + 4);
            float4 v0 = *(const float4*)(r1 + q * 16);
            float4 v1 = *(const float4*)(r1 + q * 16 + 4);
            h0[q*8+0]=u0.x; h0[q*8+1]=u0.y; h0[q*8+2]=u0.z; h0[q*8+3]=u0.w;
            h0[q*8+4]=u1.x; h0[q*8+5]=u1.y; h0[q*8+6]=u1.z; h0[q*8+7]=u1.w;
            h1[q*8+0]=v0.x; h1[q*8+1]=v0.y; h1[q*8+2]=v0.z; h1[q*8+3]=v0.w;
            h1[q*8+4]=v1.x; h1[q*8+5]=v1.y; h1[q*8+6]=v1.z; h1[q*8+7]=v1.w;
        }
    }

    f32x16 acc0 = {};
    f32x16 acc1 = {};
    float ea0 = 1.f, ea1 = 1.f;

    #pragma unroll
    for (int step = 0; step < NSTEP; ++step) {
        const int j = step >> 1;
        if ((step & 1) == 0) {
            if (j < 32) {
                const float w0 = We[j], w1 = We[32 + j], w2 = We[64 + j], bb = be[j];
                ea0 = fmaxf(fmaf(a02, w2, fmaf(a01, w1, fmaf(a00, w0, bb))), 0.f);
                ea1 = fmaxf(fmaf(a12, w2, fmaf(a11, w1, fmaf(a10, w0, bb))), 0.f);
            } else { ea0 = 1.f; ea1 = 1.f; }
        }
        short8v A0, A1;
        #pragma unroll
        for (int t = 0; t < 8; ++t) {
            A0[t] = (short)bfb(ea0 * h0[(step & 1) * 8 + t]);
            A1[t] = (short)bfb(ea1 * h1[(step & 1) * 8 + t]);
        }
        const short8v B = *(const short8v*)(bfrag + ((step * 64 + lane) << 3));
        acc0 = __builtin_amdgcn_mfma_f32_32x32x16_bf16(A0, B, acc0, 0, 0, 0);
        acc1 = __builtin_amdgcn_mfma_f32_32x32x16_bf16(A1, B, acc1, 0, 0, 0);
    }

    const int o = lane & 31;
    #pragma unroll
    for (int reg = 0; reg < 16; ++reg) {
        const int r = (reg & 3) + 8 * (reg >> 2) + 4 * hi;
        const int d0 = dst_sorted[ebase + r];
        const int d1 = dst_sorted[ebase + 32 + r];
        atomicAdd(agg + d0 * H + o, acc0[reg]);
        atomicAdd(agg + d1 * H + o, acc1[reg]);
    }
}

// --------------------------------------- fused root + relu + residual, agg:=0
__global__ __launch_bounds__(256) void finalize_k(
    float* __restrict__ agg, const float* __restrict__ sin,
    const float* __restrict__ Wroot, const float* __restrict__ bconv,
    float* __restrict__ sout)
{
    int gid = blockIdx.x * 256 + threadIdx.x;
    if (gid >= N_NODES * H) return;
    int n = gid >> 5, o = gid & 31;
    float a = agg[gid];
    agg[gid] = 0.f;                           // re-arm for next layer
    float acc = bconv[o];
    const float* row = sin + n * H;
    #pragma unroll
    for (int i = 0; i < H; ++i)
        acc = fmaf(row[i], Wroot[i * H + o], acc);
    sout[gid] = fmaxf(a + acc, 0.f) + sin[gid];
}

// ---------------------------------------------------------------- pooling
__global__ __launch_bounds__(256) void pool_k(
    const float* __restrict__ s, const int* __restrict__ batch,
    float* __restrict__ pooled)
{
    int gid = blockIdx.x * 256 + threadIdx.x;
    if (gid >= N_NODES * H) return;
    int n = gid >> 5, o = gid & 31;
    atomicAdd(pooled + batch[n] * H + o, s[gid]);
}

// ---------------------------------------------------------------- MLP head
__global__ __launch_bounds__(128) void mlp_k(
    const float* __restrict__ pooled,
    const float* __restrict__ W1, const float* __restrict__ b1,
    const float* __restrict__ W2, const float* __restrict__ b2,
    const float* __restrict__ W3, const float* __restrict__ b3,
    float* __restrict__ out)
{
    __shared__ float p[H];
    __shared__ float h1[128];
    __shared__ float h2[64];
    const int g = blockIdx.x, t = threadIdx.x;
    if (t < H) p[t] = pooled[g * H + t];
    __syncthreads();
    float a = b1[t];
    #pragma unroll
    for (int i = 0; i < H; ++i)
        a = fmaf(p[i], W1[i * 128 + t], a);
    h1[t] = fmaxf(a, 0.f);
    __syncthreads();
    if (t < 64) {
        float a2 = b2[t];
        #pragma unroll 4
        for (int i = 0; i < 128; ++i)
            a2 = fmaf(h1[i], W2[i * 64 + t], a2);
        h2[t] = fmaxf(a2, 0.f);
    }
    __syncthreads();
    if (t < 64) {
        float v = h2[t] * W3[t];
        #pragma unroll
        for (int off = 32; off > 0; off >>= 1)
            v += __shfl_down(v, off);
        if (t == 0) out[g] = v + b3[0];
    }
}

// ---------------------------------------------------------------- launcher
extern "C" void kernel_launch(void* const* d_in, const int* in_sizes, int n_in,
                              void* d_out, int out_size, void* d_ws, size_t ws_size,
                              hipStream_t stream)
{
    const float* x     = (const float*)d_in[0];
    const int*   ei    = (const int*)  d_in[1];
    const float* eattr = (const float*)d_in[2];
    const int*   batch = (const int*)  d_in[3];
    const float* Wn    = (const float*)d_in[4];
    const float* bn    = (const float*)d_in[5];
    const float* We    = (const float*)d_in[6];
    const float* be    = (const float*)d_in[7];
    const float* Wnn   = (const float*)d_in[8];
    const float* bnn   = (const float*)d_in[9];
    const float* Wroot = (const float*)d_in[10];
    const float* bconv = (const float*)d_in[11];
    const float* W1    = (const float*)d_in[12];
    const float* b1    = (const float*)d_in[13];
    const float* W2    = (const float*)d_in[14];
    const float* b2    = (const float*)d_in[15];
    const float* W3    = (const float*)d_in[16];
    const float* b3    = (const float*)d_in[17];
    float* out = (float*)d_out;

    // ws layout: s0 | s1 | agg | hist | pooled | cursor | sorted | dsts | bfrag
    float* s0     = (float*)d_ws;                       // N*H
    float* s1     = s0 + N_NODES * H;                   // N*H
    float* agg    = s1 + N_NODES * H;                   // N*H
    int*   hist   = (int*)(agg + N_NODES * H);          // N
    float* pooled = (float*)(hist + N_NODES);           // G*H
    int*   cursor = (int*)(pooled + G_GRAPHS * H);      // N
    int*   sorted = cursor + N_NODES;                   // E
    int*   dsts   = sorted + N_EDGES;                   // E
    unsigned short* bfrag = (unsigned short*)(dsts + N_EDGES); // 3*66*512

    const int* ei_dst = ei + N_EDGES;

    const dim3 blk(256);
    const int nw_grid = (N_NODES * H + 255) / 256;   // 3750
    const int e_grid  = (N_EDGES + 255) / 256;       // 469
    const int w_grid  = (3 * NSTEP * 512 + 255) / 256;

    // one memset covers agg + hist + pooled (contiguous)
    hipMemsetAsync(agg, 0,
                   (size_t)(N_NODES * H + N_NODES + G_GRAPHS * H) * sizeof(float),
                   stream);

    wconv_k<<<w_grid, blk, 0, stream>>>(Wnn, bnn, bfrag);
    node_embed_k<<<nw_grid, blk, 0, stream>>>(x, Wn, bn, s0);

    hist_k<<<e_grid, blk, 0, stream>>>(ei_dst, hist);
    scan_k<<<1, 1024, 0, stream>>>(hist, cursor);
    scatter_k<<<e_grid, blk, 0, stream>>>(ei_dst, cursor, sorted, dsts);

    const float* sin = s0;
    float* sout = s1;
    for (int k = 0; k < 3; ++k) {
        edge_mfma_k<<<e_grid, blk, 0, stream>>>(sin, eattr, ei, We, be,
                                                bfrag + k * NSTEP * 512,
                                                sorted, dsts, agg);
        finalize_k<<<nw_grid, blk, 0, stream>>>(agg, sin,
                                                Wroot + k * H * H,
                                                bconv + k * H,
                                                sout);
        const float* tmp = sout; sout = (float*)sin; sin = tmp;
    }
    // after 3 layers: result is in s1 (s0->s1, s1->s0, s0->s1)

    pool_k<<<nw_grid, blk, 0, stream>>>(s1, batch, pooled);
    mlp_k<<<G_GRAPHS, 128, 0, stream>>>(pooled, W1, b1, W2, b2, W3, b3, out);
}

// Round 4
// 202.145 us; speedup vs baseline: 1.1137x; 1.1137x over previous
//
#include <hip/hip_runtime.h>
#include <hip/hip_bf16.h>

#define N_NODES 30000
#define N_EDGES 120000
#define IN_DIM  9
#define H       32
#define G_GRAPHS 256
#define NSTEP   66   // K = 33*32 = 1056, K-step 16

typedef __attribute__((ext_vector_type(8)))  short short8v;
typedef __attribute__((ext_vector_type(16))) float f32x16;

__device__ __forceinline__ unsigned short bfb(float x) {
    __hip_bfloat16 h = __float2bfloat16(x);
    return __builtin_bit_cast(unsigned short, h);
}
__device__ __forceinline__ float b2f(unsigned short u) {
    unsigned int x = ((unsigned int)u) << 16;
    return __builtin_bit_cast(float, x);
}

// ------------------------------------------------- weights -> bf16 frag order
// bfrag[k][step][lane][t] = Wf_k[step*16 + (lane>>5)*8 + t , lane&31]
// Wf_k = [Wnn_k (1024x32); bnn_k (32x32)]
__global__ __launch_bounds__(256) void wconv_k(
    const float* __restrict__ Wnn, const float* __restrict__ bnn,
    unsigned short* __restrict__ bfrag)
{
    int gid = blockIdx.x * 256 + threadIdx.x;
    if (gid >= 3 * NSTEP * 512) return;
    int layer = gid / (NSTEP * 512);
    int rem   = gid % (NSTEP * 512);
    int step  = rem >> 9;
    int lane  = (rem >> 3) & 63;
    int t     = gid & 7;
    int krow  = step * 16 + ((lane >> 5) << 3) + t;   // 0..1055
    int col   = lane & 31;
    float v = (krow < 1024) ? Wnn[layer * 32768 + krow * 32 + col]
                            : bnn[layer * 1024 + (krow - 1024) * 32 + col];
    bfrag[gid] = bfb(v);
}

// ---------------------------------------------------------------- node embed
__global__ __launch_bounds__(256) void node_embed_k(
    const float* __restrict__ x, const float* __restrict__ Wn,
    const float* __restrict__ bn, float* __restrict__ s)
{
    int gid = blockIdx.x * 256 + threadIdx.x;
    if (gid >= N_NODES * H) return;
    int n = gid >> 5, o = gid & 31;
    float acc = bn[o];
    #pragma unroll
    for (int i = 0; i < IN_DIM; ++i)
        acc = fmaf(x[n * IN_DIM + i], Wn[i * H + o], acc);
    s[gid] = fmaxf(acc, 0.f);
}

// ------------------------------------------------------ counting sort by dst
__global__ __launch_bounds__(256) void hist_k(
    const int* __restrict__ dst, int* __restrict__ hist)
{
    int e = blockIdx.x * 256 + threadIdx.x;
    if (e < N_EDGES) atomicAdd(&hist[dst[e]], 1);
}

// 1-block exclusive scan over 30000 counters -> cursor (end-ptrs after scatter)
__global__ __launch_bounds__(1024) void scan_k(
    const int* __restrict__ hist, int* __restrict__ cursor)
{
    __shared__ int wsum[16];
    const int t = threadIdx.x;
    const int lane = t & 63, wid = t >> 6;
    const int CH = 30;                       // 1024*30 = 30720 >= 30000
    const int base = t * CH;
    int v[CH]; int sum = 0;
    #pragma unroll
    for (int i = 0; i < CH; ++i) {
        int idx = base + i;
        int x = (idx < N_NODES) ? hist[idx] : 0;
        v[i] = x; sum += x;
    }
    int incl = sum;
    #pragma unroll
    for (int off = 1; off < 64; off <<= 1) {
        int tmp = __shfl_up(incl, off);
        if (lane >= off) incl += tmp;
    }
    if (lane == 63) wsum[wid] = incl;
    __syncthreads();
    if (wid == 0 && lane < 16) {
        int wv = wsum[lane];
        #pragma unroll
        for (int off = 1; off < 16; off <<= 1) {
            int tmp = __shfl_up(wv, off);
            if (lane >= off) wv += tmp;
        }
        wsum[lane] = wv;                     // inclusive wave totals
    }
    __syncthreads();
    int excl = incl - sum + (wid > 0 ? wsum[wid - 1] : 0);
    int run = excl;
    #pragma unroll
    for (int i = 0; i < CH; ++i) {
        int idx = base + i;
        if (idx < N_NODES) cursor[idx] = run;
        run += v[i];
    }
}

__global__ __launch_bounds__(256) void scatter_k(
    const int* __restrict__ dst, int* __restrict__ cursor,
    int* __restrict__ sorted_eid)
{
    int e = blockIdx.x * 256 + threadIdx.x;
    if (e >= N_EDGES) return;
    int pos = atomicAdd(&cursor[dst[e]], 1);
    sorted_eid[pos] = e;
}

// ------------------------------------------------------------ edge conv MFMA
// Streaming (original) edge order -> fully coalesced reads. No atomics:
// message stored dense to msg[e][o] in bf16, gathered later via CSR.
// A-frag: row=lane&31 (edge), k=(lane>>5)*8+t
// D-frag: col=lane&31 (=o), row=(reg&3)+8*(reg>>2)+4*(lane>>5)
__global__ __launch_bounds__(256) void edge_mfma_k(
    const float* __restrict__ s, const float* __restrict__ eattr,
    const int* __restrict__ ei, const float* __restrict__ We,
    const float* __restrict__ be, const unsigned short* __restrict__ bfrag,
    unsigned short* __restrict__ msg)
{
    const int wave = threadIdx.x >> 6;
    const int lane = threadIdx.x & 63;
    const int ebase = blockIdx.x * 256 + wave * 64;
    if (ebase >= N_EDGES) return;            // 120000 % 64 == 0
    const int er = lane & 31;
    const int hi = lane >> 5;

    const int e0 = ebase + er;
    const int e1 = ebase + 32 + er;

    const float a00 = eattr[e0 * 3 + 0], a01 = eattr[e0 * 3 + 1], a02 = eattr[e0 * 3 + 2];
    const float a10 = eattr[e1 * 3 + 0], a11 = eattr[e1 * 3 + 1], a12 = eattr[e1 * 3 + 2];

    const int src0 = ei[e0], src1 = ei[e1];

    float h0[16], h1[16];
    {
        const float* r0 = s + src0 * H + hi * 8;
        const float* r1 = s + src1 * H + hi * 8;
        #pragma unroll
        for (int q = 0; q < 2; ++q) {
            float4 u0 = *(const float4*)(r0 + q * 16);
            float4 u1 = *(const float4*)(r0 + q * 16 + 4);
            float4 v0 = *(const float4*)(r1 + q * 16);
            float4 v1 = *(const float4*)(r1 + q * 16 + 4);
            h0[q*8+0]=u0.x; h0[q*8+1]=u0.y; h0[q*8+2]=u0.z; h0[q*8+3]=u0.w;
            h0[q*8+4]=u1.x; h0[q*8+5]=u1.y; h0[q*8+6]=u1.z; h0[q*8+7]=u1.w;
            h1[q*8+0]=v0.x; h1[q*8+1]=v0.y; h1[q*8+2]=v0.z; h1[q*8+3]=v0.w;
            h1[q*8+4]=v1.x; h1[q*8+5]=v1.y; h1[q*8+6]=v1.z; h1[q*8+7]=v1.w;
        }
    }

    f32x16 acc0 = {};
    f32x16 acc1 = {};
    float ea0 = 1.f, ea1 = 1.f;

    #pragma unroll
    for (int step = 0; step < NSTEP; ++step) {
        const int j = step >> 1;
        if ((step & 1) == 0) {
            if (j < 32) {
                const float w0 = We[j], w1 = We[32 + j], w2 = We[64 + j], bb = be[j];
                ea0 = fmaxf(fmaf(a02, w2, fmaf(a01, w1, fmaf(a00, w0, bb))), 0.f);
                ea1 = fmaxf(fmaf(a12, w2, fmaf(a11, w1, fmaf(a10, w0, bb))), 0.f);
            } else { ea0 = 1.f; ea1 = 1.f; }
        }
        short8v A0, A1;
        #pragma unroll
        for (int t = 0; t < 8; ++t) {
            A0[t] = (short)bfb(ea0 * h0[(step & 1) * 8 + t]);
            A1[t] = (short)bfb(ea1 * h1[(step & 1) * 8 + t]);
        }
        const short8v B = *(const short8v*)(bfrag + ((step * 64 + lane) << 3));
        acc0 = __builtin_amdgcn_mfma_f32_32x32x16_bf16(A0, B, acc0, 0, 0, 0);
        acc1 = __builtin_amdgcn_mfma_f32_32x32x16_bf16(A1, B, acc1, 0, 0, 0);
    }

    const int o = lane & 31;
    #pragma unroll
    for (int reg = 0; reg < 16; ++reg) {
        const int r = (reg & 3) + 8 * (reg >> 2) + 4 * hi;
        msg[(e0 - er + r) * H + o]      = bfb(acc0[reg]);
        msg[(e0 - er + 32 + r) * H + o] = bfb(acc1[reg]);
    }
}

// ----------------------- fused gather + root + relu + residual (no atomics)
__global__ __launch_bounds__(256) void finalize_k(
    const unsigned short* __restrict__ msg, const int* __restrict__ sorted_eid,
    const int* __restrict__ endptr, const float* __restrict__ sin,
    const float* __restrict__ Wroot, const float* __restrict__ bconv,
    float* __restrict__ sout)
{
    int gid = blockIdx.x * 256 + threadIdx.x;
    if (gid >= N_NODES * H) return;
    int n = gid >> 5, o = gid & 31;
    float acc = bconv[o];
    const float* row = sin + n * H;
    #pragma unroll
    for (int i = 0; i < H; ++i)
        acc = fmaf(row[i], Wroot[i * H + o], acc);
    const int p0 = (n == 0) ? 0 : endptr[n - 1];
    const int p1 = endptr[n];
    for (int p = p0; p < p1; ++p) {
        const int e = sorted_eid[p];
        acc += b2f(msg[e * H + o]);
    }
    sout[gid] = fmaxf(acc, 0.f) + sin[gid];
}

// ---------------------------------------------------------------- pooling
__global__ __launch_bounds__(256) void pool_k(
    const float* __restrict__ s, const int* __restrict__ batch,
    float* __restrict__ pooled)
{
    int gid = blockIdx.x * 256 + threadIdx.x;
    if (gid >= N_NODES * H) return;
    int n = gid >> 5, o = gid & 31;
    atomicAdd(pooled + batch[n] * H + o, s[gid]);
}

// ---------------------------------------------------------------- MLP head
__global__ __launch_bounds__(128) void mlp_k(
    const float* __restrict__ pooled,
    const float* __restrict__ W1, const float* __restrict__ b1,
    const float* __restrict__ W2, const float* __restrict__ b2,
    const float* __restrict__ W3, const float* __restrict__ b3,
    float* __restrict__ out)
{
    __shared__ float p[H];
    __shared__ float h1[128];
    __shared__ float h2[64];
    const int g = blockIdx.x, t = threadIdx.x;
    if (t < H) p[t] = pooled[g * H + t];
    __syncthreads();
    float a = b1[t];
    #pragma unroll
    for (int i = 0; i < H; ++i)
        a = fmaf(p[i], W1[i * 128 + t], a);
    h1[t] = fmaxf(a, 0.f);
    __syncthreads();
    if (t < 64) {
        float a2 = b2[t];
        #pragma unroll 4
        for (int i = 0; i < 128; ++i)
            a2 = fmaf(h1[i], W2[i * 64 + t], a2);
        h2[t] = fmaxf(a2, 0.f);
    }
    __syncthreads();
    if (t < 64) {
        float v = h2[t] * W3[t];
        #pragma unroll
        for (int off = 32; off > 0; off >>= 1)
            v += __shfl_down(v, off);
        if (t == 0) out[g] = v + b3[0];
    }
}

// ---------------------------------------------------------------- launcher
extern "C" void kernel_launch(void* const* d_in, const int* in_sizes, int n_in,
                              void* d_out, int out_size, void* d_ws, size_t ws_size,
                              hipStream_t stream)
{
    const float* x     = (const float*)d_in[0];
    const int*   ei    = (const int*)  d_in[1];
    const float* eattr = (const float*)d_in[2];
    const int*   batch = (const int*)  d_in[3];
    const float* Wn    = (const float*)d_in[4];
    const float* bn    = (const float*)d_in[5];
    const float* We    = (const float*)d_in[6];
    const float* be    = (const float*)d_in[7];
    const float* Wnn   = (const float*)d_in[8];
    const float* bnn   = (const float*)d_in[9];
    const float* Wroot = (const float*)d_in[10];
    const float* bconv = (const float*)d_in[11];
    const float* W1    = (const float*)d_in[12];
    const float* b1    = (const float*)d_in[13];
    const float* W2    = (const float*)d_in[14];
    const float* b2    = (const float*)d_in[15];
    const float* W3    = (const float*)d_in[16];
    const float* b3    = (const float*)d_in[17];
    float* out = (float*)d_out;

    // ws: s0 | s1 | hist | pooled | cursor | sorted | bfrag | msg
    float* s0     = (float*)d_ws;                         // N*H f32
    float* s1     = s0 + N_NODES * H;                     // N*H f32
    int*   hist   = (int*)(s1 + N_NODES * H);             // N
    float* pooled = (float*)(hist + N_NODES);             // G*H
    int*   cursor = (int*)(pooled + G_GRAPHS * H);        // N
    int*   sorted = cursor + N_NODES;                     // E
    unsigned short* bfrag = (unsigned short*)(sorted + N_EDGES); // 3*66*512
    unsigned short* msg   = bfrag + 3 * NSTEP * 512;      // E*H bf16

    const int* ei_dst = ei + N_EDGES;

    const dim3 blk(256);
    const int nw_grid = (N_NODES * H + 255) / 256;   // 3750
    const int e_grid  = (N_EDGES + 255) / 256;       // 469
    const int w_grid  = (3 * NSTEP * 512 + 255) / 256;

    // zero hist + pooled (contiguous)
    hipMemsetAsync(hist, 0, (size_t)(N_NODES + G_GRAPHS * H) * sizeof(int), stream);

    wconv_k<<<w_grid, blk, 0, stream>>>(Wnn, bnn, bfrag);
    node_embed_k<<<nw_grid, blk, 0, stream>>>(x, Wn, bn, s0);

    hist_k<<<e_grid, blk, 0, stream>>>(ei_dst, hist);
    scan_k<<<1, 1024, 0, stream>>>(hist, cursor);
    scatter_k<<<e_grid, blk, 0, stream>>>(ei_dst, cursor, sorted);
    // after scatter_k, cursor[n] == end offset of node n's segment

    const float* sin = s0;
    float* sout = s1;
    for (int k = 0; k < 3; ++k) {
        edge_mfma_k<<<e_grid, blk, 0, stream>>>(sin, eattr, ei, We, be,
                                                bfrag + k * NSTEP * 512, msg);
        finalize_k<<<nw_grid, blk, 0, stream>>>(msg, sorted, cursor, sin,
                                                Wroot + k * H * H,
                                                bconv + k * H, sout);
        const float* tmp = sout; sout = (float*)sin; sin = tmp;
    }
    // after 3 layers: result in s1

    pool_k<<<nw_grid, blk, 0, stream>>>(s1, batch, pooled);
    mlp_k<<<G_GRAPHS, 128, 0, stream>>>(pooled, W1, b1, W2, b2, W3, b3, out);
}

// Round 6
// 196.479 us; speedup vs baseline: 1.1458x; 1.0288x over previous
//
#include <hip/hip_runtime.h>
#include <hip/hip_bf16.h>

#define N_NODES 30000
#define N_EDGES 120000
#define IN_DIM  9
#define H       32
#define G_GRAPHS 256
#define NSTEP   66   // K = 33*32 = 1056, K-step 16

#define HIST_BLOCKS  469    // ceil(120000/256)
#define EMBED_BLOCKS 3750   // 960000/256
#define WCONV_BLOCKS 396    // 3*66*512/256

typedef __attribute__((ext_vector_type(8)))  short short8v;
typedef __attribute__((ext_vector_type(4)))  unsigned int uint4v;
typedef __attribute__((ext_vector_type(16))) float f32x16;

__device__ __forceinline__ unsigned short bfb(float x) {
    __hip_bfloat16 h = __float2bfloat16(x);
    unsigned short r;
    __builtin_memcpy(&r, &h, 2);
    return r;
}
__device__ __forceinline__ float b2f(unsigned short u) {
    unsigned int x = ((unsigned int)u) << 16;
    return __builtin_bit_cast(float, x);
}
// pack two f32 -> packed bf16x2 (v_cvt_pk_bf16_f32)
__device__ __forceinline__ unsigned int pkbf(float lo, float hi) {
    float2 f; f.x = lo; f.y = hi;
    __hip_bfloat162 b = __float22bfloat162_rn(f);
    unsigned int r;
    __builtin_memcpy(&r, &b, 4);
    return r;
}

// ------------------------- fused prologue: hist | node embed | weight conv
__global__ __launch_bounds__(256) void prologue_k(
    const int* __restrict__ dst, int* __restrict__ hist,
    const float* __restrict__ x, const float* __restrict__ Wn,
    const float* __restrict__ bn, float* __restrict__ s,
    const float* __restrict__ Wnn, const float* __restrict__ bnn,
    unsigned short* __restrict__ bfrag)
{
    const int b = blockIdx.x;
    if (b < HIST_BLOCKS) {
        int e = b * 256 + threadIdx.x;
        if (e < N_EDGES) atomicAdd(&hist[dst[e]], 1);
    } else if (b < HIST_BLOCKS + EMBED_BLOCKS) {
        int gid = (b - HIST_BLOCKS) * 256 + threadIdx.x;   // < 960000 exactly
        int n = gid >> 5, o = gid & 31;
        float acc = bn[o];
        #pragma unroll
        for (int i = 0; i < IN_DIM; ++i)
            acc = fmaf(x[n * IN_DIM + i], Wn[i * H + o], acc);
        s[gid] = fmaxf(acc, 0.f);
    } else {
        int gid = (b - HIST_BLOCKS - EMBED_BLOCKS) * 256 + threadIdx.x; // < 101376
        int layer = gid / (NSTEP * 512);
        int rem   = gid % (NSTEP * 512);
        int step  = rem >> 9;
        int lane  = (rem >> 3) & 63;
        int t     = gid & 7;
        int krow  = step * 16 + ((lane >> 5) << 3) + t;   // 0..1055
        int col   = lane & 31;
        float v = (krow < 1024) ? Wnn[layer * 32768 + krow * 32 + col]
                                : bnn[layer * 1024 + (krow - 1024) * 32 + col];
        bfrag[gid] = bfb(v);
    }
}

// 1-block exclusive scan over 30000 counters -> cursor (end-ptrs after scatter)
__global__ __launch_bounds__(1024) void scan_k(
    const int* __restrict__ hist, int* __restrict__ cursor)
{
    __shared__ int wsum[16];
    const int t = threadIdx.x;
    const int lane = t & 63, wid = t >> 6;
    const int CH = 30;                       // 1024*30 = 30720 >= 30000
    const int base = t * CH;
    int v[CH]; int sum = 0;
    #pragma unroll
    for (int i = 0; i < CH; ++i) {
        int idx = base + i;
        int xv = (idx < N_NODES) ? hist[idx] : 0;
        v[i] = xv; sum += xv;
    }
    int incl = sum;
    #pragma unroll
    for (int off = 1; off < 64; off <<= 1) {
        int tmp = __shfl_up(incl, off);
        if (lane >= off) incl += tmp;
    }
    if (lane == 63) wsum[wid] = incl;
    __syncthreads();
    if (wid == 0 && lane < 16) {
        int wv = wsum[lane];
        #pragma unroll
        for (int off = 1; off < 16; off <<= 1) {
            int tmp = __shfl_up(wv, off);
            if (lane >= off) wv += tmp;
        }
        wsum[lane] = wv;                     // inclusive wave totals
    }
    __syncthreads();
    int excl = incl - sum + (wid > 0 ? wsum[wid - 1] : 0);
    int run = excl;
    #pragma unroll
    for (int i = 0; i < CH; ++i) {
        int idx = base + i;
        if (idx < N_NODES) cursor[idx] = run;
        run += v[i];
    }
}

// rank[e] = position of edge e in dst-sorted order
__global__ __launch_bounds__(256) void scatter_k(
    const int* __restrict__ dst, int* __restrict__ cursor,
    int* __restrict__ rank)
{
    int e = blockIdx.x * 256 + threadIdx.x;
    if (e >= N_EDGES) return;
    rank[e] = atomicAdd(&cursor[dst[e]], 1);
}

// ------------------------------------------------------------ edge conv MFMA
// Streaming edge order (coalesced reads); msg written at SORTED position
// (full 64B-row stores, no atomics) so finalize reads contiguously.
// A-frag: row=lane&31 (edge), k=(lane>>5)*8+t
// D-frag: col=lane&31 (=o), row=(reg&3)+8*(reg>>2)+4*(lane>>5)
__global__ __launch_bounds__(64) void edge_mfma_k(
    const float* __restrict__ s, const float* __restrict__ eattr,
    const int* __restrict__ ei, const float* __restrict__ We,
    const float* __restrict__ be, const unsigned short* __restrict__ bfrag,
    const int* __restrict__ rank, unsigned short* __restrict__ msg)
{
    const int lane = threadIdx.x;
    const int ebase = blockIdx.x * 64;       // 120000 % 64 == 0, no tail
    const int er = lane & 31;
    const int hi = lane >> 5;

    const int e0 = ebase + er;
    const int e1 = ebase + 32 + er;

    const float a00 = eattr[e0 * 3 + 0], a01 = eattr[e0 * 3 + 1], a02 = eattr[e0 * 3 + 2];
    const float a10 = eattr[e1 * 3 + 0], a11 = eattr[e1 * 3 + 1], a12 = eattr[e1 * 3 + 2];

    const int src0 = ei[e0], src1 = ei[e1];
    const int rk = rank[ebase + lane];

    float h0[16], h1[16];
    {
        const float* r0 = s + src0 * H + hi * 8;
        const float* r1 = s + src1 * H + hi * 8;
        #pragma unroll
        for (int q = 0; q < 2; ++q) {
            float4 u0 = *(const float4*)(r0 + q * 16);
            float4 u1 = *(const float4*)(r0 + q * 16 + 4);
            float4 v0 = *(const float4*)(r1 + q * 16);
            float4 v1 = *(const float4*)(r1 + q * 16 + 4);
            h0[q*8+0]=u0.x; h0[q*8+1]=u0.y; h0[q*8+2]=u0.z; h0[q*8+3]=u0.w;
            h0[q*8+4]=u1.x; h0[q*8+5]=u1.y; h0[q*8+6]=u1.z; h0[q*8+7]=u1.w;
            h1[q*8+0]=v0.x; h1[q*8+1]=v0.y; h1[q*8+2]=v0.z; h1[q*8+3]=v0.w;
            h1[q*8+4]=v1.x; h1[q*8+5]=v1.y; h1[q*8+6]=v1.z; h1[q*8+7]=v1.w;
        }
    }

    f32x16 acc0 = {};
    f32x16 acc1 = {};
    float ea0 = 1.f, ea1 = 1.f;

    #pragma unroll
    for (int step = 0; step < NSTEP; ++step) {
        const int j = step >> 1;
        if ((step & 1) == 0) {
            if (j < 32) {
                const float w0 = We[j], w1 = We[32 + j], w2 = We[64 + j], bb = be[j];
                ea0 = fmaxf(fmaf(a02, w2, fmaf(a01, w1, fmaf(a00, w0, bb))), 0.f);
                ea1 = fmaxf(fmaf(a12, w2, fmaf(a11, w1, fmaf(a10, w0, bb))), 0.f);
            } else { ea0 = 1.f; ea1 = 1.f; }
        }
        const int hb = (step & 1) * 8;        // compile-time after full unroll
        uint4v a0i, a1i;
        #pragma unroll
        for (int q = 0; q < 4; ++q) {
            a0i[q] = pkbf(ea0 * h0[hb + 2*q], ea0 * h0[hb + 2*q + 1]);
            a1i[q] = pkbf(ea1 * h1[hb + 2*q], ea1 * h1[hb + 2*q + 1]);
        }
        const short8v A0 = __builtin_bit_cast(short8v, a0i);
        const short8v A1 = __builtin_bit_cast(short8v, a1i);
        const short8v B = *(const short8v*)(bfrag + ((step * 64 + lane) << 3));
        acc0 = __builtin_amdgcn_mfma_f32_32x32x16_bf16(A0, B, acc0, 0, 0, 0);
        acc1 = __builtin_amdgcn_mfma_f32_32x32x16_bf16(A1, B, acc1, 0, 0, 0);
    }

    const int o = er;
    #pragma unroll
    for (int reg = 0; reg < 16; ++reg) {
        const int r = (reg & 3) + 8 * (reg >> 2) + 4 * hi;
        const int p0 = __shfl(rk, r);          // rank of edge ebase+r
        const int p1 = __shfl(rk, 32 + r);     // rank of edge ebase+32+r
        msg[p0 * H + o] = bfb(acc0[reg]);
        msg[p1 * H + o] = bfb(acc1[reg]);
    }
}

// ---------- fused gather(contiguous) + root + relu + residual (+pool on last)
__global__ __launch_bounds__(256) void finalize_k(
    const unsigned short* __restrict__ msg, const int* __restrict__ endptr,
    const float* __restrict__ sin, const float* __restrict__ Wroot,
    const float* __restrict__ bconv, float* __restrict__ sout,
    const int* __restrict__ batch, float* __restrict__ pooled, int do_pool)
{
    int gid = blockIdx.x * 256 + threadIdx.x;
    if (gid >= N_NODES * H) return;
    int n = gid >> 5, o = gid & 31;
    float acc = bconv[o];
    const float* row = sin + n * H;
    #pragma unroll
    for (int i = 0; i < H; ++i)
        acc = fmaf(row[i], Wroot[i * H + o], acc);
    const int p0 = (n == 0) ? 0 : endptr[n - 1];
    const int p1 = endptr[n];
    for (int p = p0; p < p1; ++p)
        acc += b2f(msg[p * H + o]);            // contiguous sorted segment
    float val = fmaxf(acc, 0.f) + sin[gid];
    if (do_pool)
        atomicAdd(pooled + batch[n] * H + o, val);
    else
        sout[gid] = val;
}

// ---------------------------------------------------------------- MLP head
__global__ __launch_bounds__(128) void mlp_k(
    const float* __restrict__ pooled,
    const float* __restrict__ W1, const float* __restrict__ b1,
    const float* __restrict__ W2, const float* __restrict__ b2,
    const float* __restrict__ W3, const float* __restrict__ b3,
    float* __restrict__ out)
{
    __shared__ float p[H];
    __shared__ float h1[128];
    __shared__ float h2[64];
    const int g = blockIdx.x, t = threadIdx.x;
    if (t < H) p[t] = pooled[g * H + t];
    __syncthreads();
    float a = b1[t];
    #pragma unroll
    for (int i = 0; i < H; ++i)
        a = fmaf(p[i], W1[i * 128 + t], a);
    h1[t] = fmaxf(a, 0.f);
    __syncthreads();
    if (t < 64) {
        float a2 = b2[t];
        #pragma unroll 4
        for (int i = 0; i < 128; ++i)
            a2 = fmaf(h1[i], W2[i * 64 + t], a2);
        h2[t] = fmaxf(a2, 0.f);
    }
    __syncthreads();
    if (t < 64) {
        float v = h2[t] * W3[t];
        #pragma unroll
        for (int off = 32; off > 0; off >>= 1)
            v += __shfl_down(v, off);
        if (t == 0) out[g] = v + b3[0];
    }
}

// ---------------------------------------------------------------- launcher
extern "C" void kernel_launch(void* const* d_in, const int* in_sizes, int n_in,
                              void* d_out, int out_size, void* d_ws, size_t ws_size,
                              hipStream_t stream)
{
    const float* x     = (const float*)d_in[0];
    const int*   ei    = (const int*)  d_in[1];
    const float* eattr = (const float*)d_in[2];
    const int*   batch = (const int*)  d_in[3];
    const float* Wn    = (const float*)d_in[4];
    const float* bn    = (const float*)d_in[5];
    const float* We    = (const float*)d_in[6];
    const float* be    = (const float*)d_in[7];
    const float* Wnn   = (const float*)d_in[8];
    const float* bnn   = (const float*)d_in[9];
    const float* Wroot = (const float*)d_in[10];
    const float* bconv = (const float*)d_in[11];
    const float* W1    = (const float*)d_in[12];
    const float* b1    = (const float*)d_in[13];
    const float* W2    = (const float*)d_in[14];
    const float* b2    = (const float*)d_in[15];
    const float* W3    = (const float*)d_in[16];
    const float* b3    = (const float*)d_in[17];
    float* out = (float*)d_out;

    // ws: s0 | s1 | hist | pooled | cursor | rank | bfrag | msg
    float* s0     = (float*)d_ws;                         // N*H f32
    float* s1     = s0 + N_NODES * H;                     // N*H f32
    int*   hist   = (int*)(s1 + N_NODES * H);             // N
    float* pooled = (float*)(hist + N_NODES);             // G*H
    int*   cursor = (int*)(pooled + G_GRAPHS * H);        // N
    int*   rank   = cursor + N_NODES;                     // E
    unsigned short* bfrag = (unsigned short*)(rank + N_EDGES); // 3*66*512
    unsigned short* msg   = bfrag + 3 * NSTEP * 512;      // E*H bf16

    const int* ei_dst = ei + N_EDGES;

    const int nw_grid = (N_NODES * H + 255) / 256;   // 3750
    const int e_grid  = N_EDGES / 64;                // 1875

    // zero hist + pooled (contiguous)
    (void)hipMemsetAsync(hist, 0, (size_t)(N_NODES + G_GRAPHS * H) * sizeof(int), stream);

    prologue_k<<<HIST_BLOCKS + EMBED_BLOCKS + WCONV_BLOCKS, 256, 0, stream>>>(
        ei_dst, hist, x, Wn, bn, s0, Wnn, bnn, bfrag);
    scan_k<<<1, 1024, 0, stream>>>(hist, cursor);
    scatter_k<<<(N_EDGES + 255) / 256, 256, 0, stream>>>(ei_dst, cursor, rank);
    // after scatter_k, cursor[n] == end offset of node n's sorted segment

    const float* sin = s0;
    float* sout = s1;
    for (int k = 0; k < 3; ++k) {
        edge_mfma_k<<<e_grid, 64, 0, stream>>>(sin, eattr, ei, We, be,
                                               bfrag + k * NSTEP * 512,
                                               rank, msg);
        finalize_k<<<nw_grid, 256, 0, stream>>>(msg, cursor, sin,
                                                Wroot + k * H * H,
                                                bconv + k * H, sout,
                                                batch, pooled, (k == 2) ? 1 : 0);
        const float* tmp = sout; sout = (float*)sin; sin = tmp;
    }

    mlp_k<<<G_GRAPHS, 128, 0, stream>>>(pooled, W1, b1, W2, b2, W3, b3, out);
}